// Round 5
// baseline (332.103 us; speedup 1.0000x reference)
//
#include <hip/hip_runtime.h>
#include <math.h>

#define NCL 21
#define CIN 256
#define HW 4096
#define PADK 24
#define NB 2

static __device__ __forceinline__ float fastrcp(float x) {
  return __builtin_amdgcn_rcpf(x);
}

// ---------------------------------------------------------------------------
// Kernel A: f1/f2 = 1x1 conv (w @ feat + b), PLUS the out 128->64 bilinear
// downsample (merged k_outr), PLUS zero-fill of lbuf/corr_out (replaces
// memsets). Block = 16 q x 16 c-chunks of 16 channels; LDS reduction.
#define QT 16
#define CCH 16
__global__ __launch_bounds__(256) void k_feat(
    const float* __restrict__ feat, const float* __restrict__ w1,
    const float* __restrict__ b1, const float* __restrict__ w2,
    const float* __restrict__ b2, const float* __restrict__ outp,
    float* __restrict__ f1T, float* __restrict__ f2, float* __restrict__ otT,
    float* __restrict__ lbuf, float* __restrict__ corr_out) {
  const int t = threadIdx.x;
  const int bid = blockIdx.y * (HW / QT) + blockIdx.x;  // 0..511
  // zero-fill: corr_out = 43008 float4 (84/block), lbuf = 8192 f (16/block)
  {
    float4* co4 = (float4*)corr_out;
    const int base = bid * 84;
    for (int o = t; o < 84; o += 256) co4[base + o] = make_float4(0, 0, 0, 0);
    if (t < 16) lbuf[bid * 16 + t] = 0.f;
  }
  // merged k_outr: 172032 elements, 336 per block
  for (int o = t; o < 336; o += 256) {
    int idx = bid * 336 + o;
    int p = idx & (HW - 1);
    int nk = idx >> 12;
    int i = p >> 6, j = p & 63;
    double sy = (double)i * (127.0 / 63.0);
    double sx = (double)j * (127.0 / 63.0);
    int y0 = (int)sy, x0 = (int)sx;
    float wy = (float)(sy - y0), wx = (float)(sx - x0);
    int y1 = min(y0 + 1, 127), x1 = min(x0 + 1, 127);
    const float* src = outp + (size_t)nk * (128 * 128);
    float v00 = src[y0 * 128 + x0], v10 = src[y1 * 128 + x0];
    float v01 = src[y0 * 128 + x1], v11 = src[y1 * 128 + x1];
    float r0 = v00 * (1.f - wy) + v10 * wy;
    float r1 = v01 * (1.f - wy) + v11 * wy;
    float val = r0 * (1.f - wx) + r1 * wx;
    int n = nk / NCL, c = nk % NCL;
    otT[((size_t)n * HW + p) * PADK + c] = val;
  }
  const int qi = t & 15, ch = t >> 4;
  const int n = blockIdx.y;
  const int q = blockIdx.x * QT + qi;
  const int c0 = ch * CCH;
  const float* fp = feat + ((size_t)n * CIN + c0) * HW + q;
  float a1[NCL], a2[NCL];
#pragma unroll
  for (int k = 0; k < NCL; ++k) { a1[k] = 0.f; a2[k] = 0.f; }
#pragma unroll
  for (int cc = 0; cc < CCH; ++cc) {
    float v = fp[(size_t)cc * HW];
#pragma unroll
    for (int k = 0; k < NCL; ++k) {
      a1[k] = fmaf(v, w1[k * CIN + c0 + cc], a1[k]);
      a2[k] = fmaf(v, w2[k * CIN + c0 + cc], a2[k]);
    }
  }
  __shared__ float p1[CCH][QT][NCL];
  __shared__ float p2[CCH][QT][NCL];
#pragma unroll
  for (int k = 0; k < NCL; ++k) { p1[ch][qi][k] = a1[k]; p2[ch][qi][k] = a2[k]; }
  __syncthreads();
  for (int o = t; o < QT * NCL; o += 256) {
    int qq = o & 15, k = o >> 4;
    float s1 = b1[k], s2 = b2[k];
#pragma unroll
    for (int c = 0; c < CCH; ++c) { s1 += p1[c][qq][k]; s2 += p2[c][qq][k]; }
    int qg = blockIdx.x * QT + qq;
    f1T[((size_t)n * HW + qg) * PADK + k] = s1;
    f2[((size_t)n * NCL + k) * HW + qg] = s2;
  }
}

// ---------------------------------------------------------------------------
// Kernel C: l[n][p] += sum_q exp(S[n][p][q]) over a q-quarter. r3 structure
// (s_load f1 rows; the r4 LDS variant blew VGPR to 208 and regressed).
#define PT 16
__global__ __launch_bounds__(256) void k_stats(
    const float* __restrict__ f1T, const float* __restrict__ f2,
    float* __restrict__ l) {
  const int t = threadIdx.x;
  const int n = blockIdx.z;
  const int pbase = blockIdx.x * PT;
  const int q0 = blockIdx.y * 1024 + t * 4;
  const float* f2n = f2 + (size_t)n * NCL * HW;
  const float* f1n = f1T + ((size_t)n * HW + pbase) * PADK;
  const float SCALE = 1.0f / sqrtf(21.0f);
  float4 fq[NCL];
#pragma unroll
  for (int k = 0; k < NCL; ++k)
    fq[k] = *(const float4*)(f2n + (size_t)k * HW + q0);
  float sums[PT];
#pragma unroll
  for (int p = 0; p < PT; ++p) {
    const float* f1p = f1n + p * PADK;  // uniform -> s_load
    float s0 = 0.f, s1 = 0.f, s2 = 0.f, s3 = 0.f;
#pragma unroll
    for (int k = 0; k < NCL; ++k) {
      float a = f1p[k];
      s0 = fmaf(a, fq[k].x, s0);
      s1 = fmaf(a, fq[k].y, s1);
      s2 = fmaf(a, fq[k].z, s2);
      s3 = fmaf(a, fq[k].w, s3);
    }
    sums[p] = __expf(s0 * SCALE) + __expf(s1 * SCALE) + __expf(s2 * SCALE) +
              __expf(s3 * SCALE);
  }
  __shared__ float part[4][PT];
  const int wave = t >> 6, lane = t & 63;
#pragma unroll
  for (int p = 0; p < PT; ++p) {
    float s = sums[p];
    for (int off = 32; off > 0; off >>= 1) s += __shfl_xor(s, off, 64);
    if (lane == 0) part[wave][p] = s;
  }
  __syncthreads();
  if (t < PT) {
    float tot = part[0][t] + part[1][t] + part[2][t] + part[3][t];
    atomicAdd(l + (size_t)n * HW + pbase + t, tot);
  }
}

// ---------------------------------------------------------------------------
// Kernel D: corr_out[n][c][q] += sum_p otT[n][p][c] * exp(S[p][q]) / l[p].
// 4 q per thread (float4): 4 independent FMA chains, ~180 VALU per 6 s_loads
// per p-iter. VGPR ~200 -> 2 waves/SIMD; grid 4x64x2 = 512 blocks = exactly
// the VGPR-limited device capacity.
#define DPS 64
__global__ __launch_bounds__(256, 2) void k_corrout(
    const float* __restrict__ f1T, const float* __restrict__ f2,
    const float* __restrict__ otT, const float* __restrict__ l,
    float* __restrict__ corr_out) {
  const int t = threadIdx.x;
  const int n = blockIdx.z;
  const int q0 = blockIdx.x * 1024 + t * 4;
  const int pbase = blockIdx.y * DPS;
  const float* f2n = f2 + (size_t)n * NCL * HW;
  const float SCALE = 1.0f / sqrtf(21.0f);
  float4 fq[NCL];
#pragma unroll
  for (int k = 0; k < NCL; ++k)
    fq[k] = *(const float4*)(f2n + (size_t)k * HW + q0);
  float4 acc[NCL];
#pragma unroll
  for (int k = 0; k < NCL; ++k) acc[k] = make_float4(0.f, 0.f, 0.f, 0.f);
  const float* f1p = f1T + ((size_t)n * HW + pbase) * PADK;
  const float* otp = otT + ((size_t)n * HW + pbase) * PADK;
  const float* lp = l + (size_t)n * HW + pbase;
  for (int p = 0; p < DPS; ++p) {
    float s0 = 0.f, s1 = 0.f, s2 = 0.f, s3 = 0.f;
#pragma unroll
    for (int k = 0; k < NCL; ++k) {
      float a = f1p[p * PADK + k];  // uniform -> s_load
      s0 = fmaf(a, fq[k].x, s0);
      s1 = fmaf(a, fq[k].y, s1);
      s2 = fmaf(a, fq[k].z, s2);
      s3 = fmaf(a, fq[k].w, s3);
    }
    float il = fastrcp(lp[p]);
    float w0 = __expf(s0 * SCALE) * il;
    float w1 = __expf(s1 * SCALE) * il;
    float w2 = __expf(s2 * SCALE) * il;
    float w3 = __expf(s3 * SCALE) * il;
#pragma unroll
    for (int c = 0; c < NCL; ++c) {
      float o = otp[p * PADK + c];  // uniform -> s_load
      acc[c].x = fmaf(o, w0, acc[c].x);
      acc[c].y = fmaf(o, w1, acc[c].y);
      acc[c].z = fmaf(o, w2, acc[c].z);
      acc[c].w = fmaf(o, w3, acc[c].w);
    }
  }
  float* co = corr_out + (size_t)n * NCL * HW + q0;
#pragma unroll
  for (int c = 0; c < NCL; ++c) {
    atomicAdd(co + (size_t)c * HW + 0, acc[c].x);
    atomicAdd(co + (size_t)c * HW + 1, acc[c].y);
    atomicAdd(co + (size_t)c * HW + 2, acc[c].z);
    atomicAdd(co + (size_t)c * HW + 3, acc[c].w);
  }
}

// ---------------------------------------------------------------------------
// Kernel E1: unnormalized sampled rows (min/max norm is scale-invariant ->
// softmax denominator skipped). Rows parked in the output-0 slots.
__global__ __launch_bounds__(256) void k_rows(
    const float* __restrict__ f1T, const float* __restrict__ f2,
    const int* __restrict__ index, float* __restrict__ out0) {
  const int t = threadIdx.x;
  const int qc = blockIdx.x;  // 0..3
  const int i = blockIdx.y;
  const int n = blockIdx.z;
  int p = index[i];
  p = max(0, min(p, HW - 1));
  const float* f1p = f1T + ((size_t)n * HW + p) * PADK;  // uniform
  const float* f2n = f2 + (size_t)n * NCL * HW;
  const float SCALE = 1.0f / sqrtf(21.0f);
  const int q0 = qc * 1024 + t * 4;
  float4 fq[NCL];
#pragma unroll
  for (int k = 0; k < NCL; ++k)
    fq[k] = *(const float4*)(f2n + (size_t)k * HW + q0);
  float s0 = 0.f, s1 = 0.f, s2 = 0.f, s3 = 0.f;
#pragma unroll
  for (int k = 0; k < NCL; ++k) {
    float a = f1p[k];
    s0 = fmaf(a, fq[k].x, s0);
    s1 = fmaf(a, fq[k].y, s1);
    s2 = fmaf(a, fq[k].z, s2);
    s3 = fmaf(a, fq[k].w, s3);
  }
  float4 r = make_float4(__expf(s0 * SCALE), __expf(s1 * SCALE),
                         __expf(s2 * SCALE), __expf(s3 * SCALE));
  *(float4*)(out0 + ((size_t)n * 128 + i) * (128 * 128) + q0) = r;
}

// ---------------------------------------------------------------------------
// Kernel E2: row -> bilinear 64->128 (in-kernel table) -> min/max norm ->
// >0.5 booleans as 1.0/0.0 (overwrites slot). 1024 threads: 16 waves/CU.
__global__ __launch_bounds__(1024) void k_norm(float* __restrict__ out0) {
  __shared__ float row[HW];
  __shared__ float redmn[16], redmx[16];
  __shared__ float wt[128];
  __shared__ int it[128];
  const int t = threadIdx.x;
  const int i = blockIdx.x;
  const int n = blockIdx.y;
  if (t < 128) {
    double s = (double)t * (63.0 / 127.0);
    int i0 = (int)s;
    wt[t] = (float)(s - i0);
    it[t] = i0;
  }
  float* slot = out0 + ((size_t)n * 128 + i) * (128 * 128);
  *(float4*)(row + t * 4) = *(const float4*)(slot + t * 4);
  __syncthreads();
  float vv[16];
  float lmn = 1e30f, lmx = -1e30f;
#pragma unroll
  for (int j = 0; j < 16; ++j) {
    int pix = t + j * 1024;
    int yy = pix >> 7, xx = pix & 127;
    int y0 = it[yy], x0 = it[xx];
    float wy = wt[yy], wx = wt[xx];
    int y1 = min(y0 + 1, 63), x1 = min(x0 + 1, 63);
    float r0 = row[y0 * 64 + x0] * (1.f - wy) + row[y1 * 64 + x0] * wy;
    float r1 = row[y0 * 64 + x1] * (1.f - wy) + row[y1 * 64 + x1] * wy;
    float v = r0 * (1.f - wx) + r1 * wx;
    vv[j] = v;
    lmn = fminf(lmn, v);
    lmx = fmaxf(lmx, v);
  }
  for (int off = 32; off > 0; off >>= 1) {
    lmn = fminf(lmn, __shfl_xor(lmn, off, 64));
    lmx = fmaxf(lmx, __shfl_xor(lmx, off, 64));
  }
  const int wave = t >> 6, lane = t & 63;
  if (lane == 0) { redmn[wave] = lmn; redmx[wave] = lmx; }
  __syncthreads();
  if (t == 0) {
    float mn = redmn[0], mx = redmx[0];
#pragma unroll
    for (int wv = 1; wv < 16; ++wv) {
      mn = fminf(mn, redmn[wv]);
      mx = fmaxf(mx, redmx[wv]);
    }
    redmn[0] = mn;
    redmx[0] = mx;
  }
  __syncthreads();
  const float mn = redmn[0];
  const float rng = redmx[0] - mn;
#pragma unroll
  for (int j = 0; j < 16; ++j) {
    int pix = t + j * 1024;
    float nrm = (vv[j] - mn) / rng;
    slot[pix] = (nrm > 0.5f) ? 1.0f : 0.0f;
  }
}

// ---------------------------------------------------------------------------
extern "C" void kernel_launch(void* const* d_in, const int* in_sizes, int n_in,
                              void* d_out, int out_size, void* d_ws,
                              size_t ws_size, hipStream_t stream) {
  (void)in_sizes; (void)n_in; (void)out_size; (void)ws_size;
  const float* feat = (const float*)d_in[0];
  const float* out  = (const float*)d_in[1];
  const float* w1   = (const float*)d_in[2];
  const float* b1   = (const float*)d_in[3];
  const float* w2   = (const float*)d_in[4];
  const float* b2   = (const float*)d_in[5];
  const int* index  = (const int*)d_in[6];

  float* ws   = (float*)d_ws;
  float* f1T  = ws;                                   // 2*4096*24 = 196608
  float* f2   = ws + 196608;                          // 2*21*4096 = 172032
  float* otT  = ws + 196608 + 172032;                 // 196608
  float* lbuf = ws + 196608 + 172032 + 196608;        // 8192

  float* out0     = (float*)d_out;                    // 2*128*128*128
  float* corr_out = out0 + (size_t)NB * 128 * 128 * 128;  // 2*21*4096

  k_feat<<<dim3(HW / QT, 2), 256, 0, stream>>>(feat, w1, b1, w2, b2, out, f1T,
                                               f2, otT, lbuf, corr_out);
  k_stats<<<dim3(HW / PT, 4, 2), 256, 0, stream>>>(f1T, f2, lbuf);
  k_rows<<<dim3(4, 128, 2), 256, 0, stream>>>(f1T, f2, index, out0);
  k_corrout<<<dim3(4, HW / DPS, 2), 256, 0, stream>>>(f1T, f2, otT, lbuf,
                                                      corr_out);
  k_norm<<<dim3(128, 2), 1024, 0, stream>>>(out0);
}

// Round 6
// 219.689 us; speedup vs baseline: 1.5117x; 1.5117x over previous
//
#include <hip/hip_runtime.h>
#include <math.h>

#define NCL 21
#define CIN 256
#define HW 4096
#define PADK 24
#define NB 2

static __device__ __forceinline__ float fastrcp(float x) {
  return __builtin_amdgcn_rcpf(x);
}

// ---------------------------------------------------------------------------
// Kernel A: f1/f2 = 1x1 conv (w @ feat + b), PLUS the out 128->64 bilinear
// downsample (merged k_outr), PLUS zero-fill of lbuf/corr_out (replaces
// memsets). Block = 16 q x 16 c-chunks of 16 channels; LDS reduction.
#define QT 16
#define CCH 16
__global__ __launch_bounds__(256) void k_feat(
    const float* __restrict__ feat, const float* __restrict__ w1,
    const float* __restrict__ b1, const float* __restrict__ w2,
    const float* __restrict__ b2, const float* __restrict__ outp,
    float* __restrict__ f1T, float* __restrict__ f2, float* __restrict__ otT,
    float* __restrict__ lbuf, float* __restrict__ corr_out) {
  const int t = threadIdx.x;
  const int bid = blockIdx.y * (HW / QT) + blockIdx.x;  // 0..511
  // zero-fill: corr_out = 43008 float4 (84/block), lbuf = 8192 f (16/block)
  {
    float4* co4 = (float4*)corr_out;
    const int base = bid * 84;
    for (int o = t; o < 84; o += 256) co4[base + o] = make_float4(0, 0, 0, 0);
    if (t < 16) lbuf[bid * 16 + t] = 0.f;
  }
  // merged k_outr: 172032 elements, 336 per block
  for (int o = t; o < 336; o += 256) {
    int idx = bid * 336 + o;
    int p = idx & (HW - 1);
    int nk = idx >> 12;
    int i = p >> 6, j = p & 63;
    double sy = (double)i * (127.0 / 63.0);
    double sx = (double)j * (127.0 / 63.0);
    int y0 = (int)sy, x0 = (int)sx;
    float wy = (float)(sy - y0), wx = (float)(sx - x0);
    int y1 = min(y0 + 1, 127), x1 = min(x0 + 1, 127);
    const float* src = outp + (size_t)nk * (128 * 128);
    float v00 = src[y0 * 128 + x0], v10 = src[y1 * 128 + x0];
    float v01 = src[y0 * 128 + x1], v11 = src[y1 * 128 + x1];
    float r0 = v00 * (1.f - wy) + v10 * wy;
    float r1 = v01 * (1.f - wy) + v11 * wy;
    float val = r0 * (1.f - wx) + r1 * wx;
    int n = nk / NCL, c = nk % NCL;
    otT[((size_t)n * HW + p) * PADK + c] = val;
  }
  const int qi = t & 15, ch = t >> 4;
  const int n = blockIdx.y;
  const int q = blockIdx.x * QT + qi;
  const int c0 = ch * CCH;
  const float* fp = feat + ((size_t)n * CIN + c0) * HW + q;
  float a1[NCL], a2[NCL];
#pragma unroll
  for (int k = 0; k < NCL; ++k) { a1[k] = 0.f; a2[k] = 0.f; }
#pragma unroll
  for (int cc = 0; cc < CCH; ++cc) {
    float v = fp[(size_t)cc * HW];
#pragma unroll
    for (int k = 0; k < NCL; ++k) {
      a1[k] = fmaf(v, w1[k * CIN + c0 + cc], a1[k]);
      a2[k] = fmaf(v, w2[k * CIN + c0 + cc], a2[k]);
    }
  }
  __shared__ float p1[CCH][QT][NCL];
  __shared__ float p2[CCH][QT][NCL];
#pragma unroll
  for (int k = 0; k < NCL; ++k) { p1[ch][qi][k] = a1[k]; p2[ch][qi][k] = a2[k]; }
  __syncthreads();
  for (int o = t; o < QT * NCL; o += 256) {
    int qq = o & 15, k = o >> 4;
    float s1 = b1[k], s2 = b2[k];
#pragma unroll
    for (int c = 0; c < CCH; ++c) { s1 += p1[c][qq][k]; s2 += p2[c][qq][k]; }
    int qg = blockIdx.x * QT + qq;
    f1T[((size_t)n * HW + qg) * PADK + k] = s1;
    f2[((size_t)n * NCL + k) * HW + qg] = s2;
  }
}

// ---------------------------------------------------------------------------
// Kernel C: l[n][p] += sum_q exp(S[n][p][q]) over a q-quarter. r3 structure
// (s_load f1 rows) — known-good; unchanged this round.
#define PT 16
__global__ __launch_bounds__(256) void k_stats(
    const float* __restrict__ f1T, const float* __restrict__ f2,
    float* __restrict__ l) {
  const int t = threadIdx.x;
  const int n = blockIdx.z;
  const int pbase = blockIdx.x * PT;
  const int q0 = blockIdx.y * 1024 + t * 4;
  const float* f2n = f2 + (size_t)n * NCL * HW;
  const float* f1n = f1T + ((size_t)n * HW + pbase) * PADK;
  const float SCALE = 1.0f / sqrtf(21.0f);
  float4 fq[NCL];
#pragma unroll
  for (int k = 0; k < NCL; ++k)
    fq[k] = *(const float4*)(f2n + (size_t)k * HW + q0);
  float sums[PT];
#pragma unroll
  for (int p = 0; p < PT; ++p) {
    const float* f1p = f1n + p * PADK;  // uniform -> s_load
    float s0 = 0.f, s1 = 0.f, s2 = 0.f, s3 = 0.f;
#pragma unroll
    for (int k = 0; k < NCL; ++k) {
      float a = f1p[k];
      s0 = fmaf(a, fq[k].x, s0);
      s1 = fmaf(a, fq[k].y, s1);
      s2 = fmaf(a, fq[k].z, s2);
      s3 = fmaf(a, fq[k].w, s3);
    }
    sums[p] = __expf(s0 * SCALE) + __expf(s1 * SCALE) + __expf(s2 * SCALE) +
              __expf(s3 * SCALE);
  }
  __shared__ float part[4][PT];
  const int wave = t >> 6, lane = t & 63;
#pragma unroll
  for (int p = 0; p < PT; ++p) {
    float s = sums[p];
    for (int off = 32; off > 0; off >>= 1) s += __shfl_xor(s, off, 64);
    if (lane == 0) part[wave][p] = s;
  }
  __syncthreads();
  if (t < PT) {
    float tot = part[0][t] + part[1][t] + part[2][t] + part[3][t];
    atomicAdd(l + (size_t)n * HW + pbase + t, tot);
  }
}

// ---------------------------------------------------------------------------
// Kernel D: corr_out[n][c][q] += sum_p otT[n][p][c] * exp(S[p][q]) / l[p].
// p-tile (64 rows of f1/ot + rcp(l)) staged in LDS; inner loop reads it via
// ds_read_b128 (5 float4 + 1 scalar per 21-float row -> ~13 LDS issues per p
// vs ~196 VALU cycles at Q=2). Rolled p-loop (unroll 1) keeps the compiler
// from hoisting LDS reads (r4's VGPR explosion). Grid 8x64x2 = 1024 blocks;
// VGPR target ~110-130 -> 4 waves/SIMD.
#define DPS 64
__global__ __launch_bounds__(256) void k_corrout(
    const float* __restrict__ f1T, const float* __restrict__ f2,
    const float* __restrict__ otT, const float* __restrict__ l,
    float* __restrict__ corr_out) {
  __shared__ float sf1[DPS * PADK];  // 1536 floats, rows 16B-aligned (96 B)
  __shared__ float sot[DPS * PADK];
  __shared__ float sil[DPS];
  const int t = threadIdx.x;
  const int n = blockIdx.z;
  const int q0 = blockIdx.x * 512 + t * 2;
  const int pbase = blockIdx.y * DPS;
  const float4* gf1 = (const float4*)(f1T + ((size_t)n * HW + pbase) * PADK);
  const float4* got = (const float4*)(otT + ((size_t)n * HW + pbase) * PADK);
  for (int o = t; o < 384; o += 256) {
    ((float4*)sf1)[o] = gf1[o];
    ((float4*)sot)[o] = got[o];
  }
  if (t < DPS) sil[t] = fastrcp(l[(size_t)n * HW + pbase + t]);
  __syncthreads();
  const float* f2n = f2 + (size_t)n * NCL * HW;
  const float SCALE = 1.0f / sqrtf(21.0f);
  float2 fq[NCL];
#pragma unroll
  for (int k = 0; k < NCL; ++k)
    fq[k] = *(const float2*)(f2n + (size_t)k * HW + q0);
  float2 acc[NCL];
#pragma unroll
  for (int k = 0; k < NCL; ++k) acc[k] = make_float2(0.f, 0.f);
#pragma unroll 1
  for (int p = 0; p < DPS; ++p) {
    const float* f1p = sf1 + p * PADK;
    const float* otp = sot + p * PADK;
    // f1 row: 5x ds_read_b128 + 1x ds_read_b32 (indices 0..20)
    float s0 = 0.f, s1 = 0.f;
#pragma unroll
    for (int k4 = 0; k4 < 5; ++k4) {
      float4 a = *(const float4*)(f1p + k4 * 4);
      s0 = fmaf(a.x, fq[k4 * 4 + 0].x, s0);
      s1 = fmaf(a.x, fq[k4 * 4 + 0].y, s1);
      s0 = fmaf(a.y, fq[k4 * 4 + 1].x, s0);
      s1 = fmaf(a.y, fq[k4 * 4 + 1].y, s1);
      s0 = fmaf(a.z, fq[k4 * 4 + 2].x, s0);
      s1 = fmaf(a.z, fq[k4 * 4 + 2].y, s1);
      s0 = fmaf(a.w, fq[k4 * 4 + 3].x, s0);
      s1 = fmaf(a.w, fq[k4 * 4 + 3].y, s1);
    }
    {
      float a20 = f1p[20];
      s0 = fmaf(a20, fq[20].x, s0);
      s1 = fmaf(a20, fq[20].y, s1);
    }
    float il = sil[p];
    float w0 = __expf(s0 * SCALE) * il;
    float w1 = __expf(s1 * SCALE) * il;
    // ot row: 5x ds_read_b128 + 1x ds_read_b32
#pragma unroll
    for (int c4 = 0; c4 < 5; ++c4) {
      float4 o = *(const float4*)(otp + c4 * 4);
      acc[c4 * 4 + 0].x = fmaf(o.x, w0, acc[c4 * 4 + 0].x);
      acc[c4 * 4 + 0].y = fmaf(o.x, w1, acc[c4 * 4 + 0].y);
      acc[c4 * 4 + 1].x = fmaf(o.y, w0, acc[c4 * 4 + 1].x);
      acc[c4 * 4 + 1].y = fmaf(o.y, w1, acc[c4 * 4 + 1].y);
      acc[c4 * 4 + 2].x = fmaf(o.z, w0, acc[c4 * 4 + 2].x);
      acc[c4 * 4 + 2].y = fmaf(o.z, w1, acc[c4 * 4 + 2].y);
      acc[c4 * 4 + 3].x = fmaf(o.w, w0, acc[c4 * 4 + 3].x);
      acc[c4 * 4 + 3].y = fmaf(o.w, w1, acc[c4 * 4 + 3].y);
    }
    {
      float o20 = otp[20];
      acc[20].x = fmaf(o20, w0, acc[20].x);
      acc[20].y = fmaf(o20, w1, acc[20].y);
    }
  }
  float* co = corr_out + (size_t)n * NCL * HW + q0;
#pragma unroll
  for (int c = 0; c < NCL; ++c) {
    atomicAdd(co + (size_t)c * HW + 0, acc[c].x);
    atomicAdd(co + (size_t)c * HW + 1, acc[c].y);
  }
}

// ---------------------------------------------------------------------------
// Kernel E1: unnormalized sampled rows (min/max norm is scale-invariant ->
// softmax denominator skipped). Rows parked in the output-0 slots.
__global__ __launch_bounds__(256) void k_rows(
    const float* __restrict__ f1T, const float* __restrict__ f2,
    const int* __restrict__ index, float* __restrict__ out0) {
  const int t = threadIdx.x;
  const int qc = blockIdx.x;  // 0..3
  const int i = blockIdx.y;
  const int n = blockIdx.z;
  int p = index[i];
  p = max(0, min(p, HW - 1));
  const float* f1p = f1T + ((size_t)n * HW + p) * PADK;  // uniform
  const float* f2n = f2 + (size_t)n * NCL * HW;
  const float SCALE = 1.0f / sqrtf(21.0f);
  const int q0 = qc * 1024 + t * 4;
  float4 fq[NCL];
#pragma unroll
  for (int k = 0; k < NCL; ++k)
    fq[k] = *(const float4*)(f2n + (size_t)k * HW + q0);
  float s0 = 0.f, s1 = 0.f, s2 = 0.f, s3 = 0.f;
#pragma unroll
  for (int k = 0; k < NCL; ++k) {
    float a = f1p[k];
    s0 = fmaf(a, fq[k].x, s0);
    s1 = fmaf(a, fq[k].y, s1);
    s2 = fmaf(a, fq[k].z, s2);
    s3 = fmaf(a, fq[k].w, s3);
  }
  float4 r = make_float4(__expf(s0 * SCALE), __expf(s1 * SCALE),
                         __expf(s2 * SCALE), __expf(s3 * SCALE));
  *(float4*)(out0 + ((size_t)n * 128 + i) * (128 * 128) + q0) = r;
}

// ---------------------------------------------------------------------------
// Kernel E2: row -> bilinear 64->128 (in-kernel table) -> min/max norm ->
// >0.5 booleans as 1.0/0.0 (overwrites slot). 1024 threads: 16 waves/CU.
__global__ __launch_bounds__(1024) void k_norm(float* __restrict__ out0) {
  __shared__ float row[HW];
  __shared__ float redmn[16], redmx[16];
  __shared__ float wt[128];
  __shared__ int it[128];
  const int t = threadIdx.x;
  const int i = blockIdx.x;
  const int n = blockIdx.y;
  if (t < 128) {
    double s = (double)t * (63.0 / 127.0);
    int i0 = (int)s;
    wt[t] = (float)(s - i0);
    it[t] = i0;
  }
  float* slot = out0 + ((size_t)n * 128 + i) * (128 * 128);
  *(float4*)(row + t * 4) = *(const float4*)(slot + t * 4);
  __syncthreads();
  float vv[16];
  float lmn = 1e30f, lmx = -1e30f;
#pragma unroll
  for (int j = 0; j < 16; ++j) {
    int pix = t + j * 1024;
    int yy = pix >> 7, xx = pix & 127;
    int y0 = it[yy], x0 = it[xx];
    float wy = wt[yy], wx = wt[xx];
    int y1 = min(y0 + 1, 63), x1 = min(x0 + 1, 63);
    float r0 = row[y0 * 64 + x0] * (1.f - wy) + row[y1 * 64 + x0] * wy;
    float r1 = row[y0 * 64 + x1] * (1.f - wy) + row[y1 * 64 + x1] * wy;
    float v = r0 * (1.f - wx) + r1 * wx;
    vv[j] = v;
    lmn = fminf(lmn, v);
    lmx = fmaxf(lmx, v);
  }
  for (int off = 32; off > 0; off >>= 1) {
    lmn = fminf(lmn, __shfl_xor(lmn, off, 64));
    lmx = fmaxf(lmx, __shfl_xor(lmx, off, 64));
  }
  const int wave = t >> 6, lane = t & 63;
  if (lane == 0) { redmn[wave] = lmn; redmx[wave] = lmx; }
  __syncthreads();
  if (t == 0) {
    float mn = redmn[0], mx = redmx[0];
#pragma unroll
    for (int wv = 1; wv < 16; ++wv) {
      mn = fminf(mn, redmn[wv]);
      mx = fmaxf(mx, redmx[wv]);
    }
    redmn[0] = mn;
    redmx[0] = mx;
  }
  __syncthreads();
  const float mn = redmn[0];
  const float rng = redmx[0] - mn;
#pragma unroll
  for (int j = 0; j < 16; ++j) {
    int pix = t + j * 1024;
    float nrm = (vv[j] - mn) / rng;
    slot[pix] = (nrm > 0.5f) ? 1.0f : 0.0f;
  }
}

// ---------------------------------------------------------------------------
extern "C" void kernel_launch(void* const* d_in, const int* in_sizes, int n_in,
                              void* d_out, int out_size, void* d_ws,
                              size_t ws_size, hipStream_t stream) {
  (void)in_sizes; (void)n_in; (void)out_size; (void)ws_size;
  const float* feat = (const float*)d_in[0];
  const float* out  = (const float*)d_in[1];
  const float* w1   = (const float*)d_in[2];
  const float* b1   = (const float*)d_in[3];
  const float* w2   = (const float*)d_in[4];
  const float* b2   = (const float*)d_in[5];
  const int* index  = (const int*)d_in[6];

  float* ws   = (float*)d_ws;
  float* f1T  = ws;                                   // 2*4096*24 = 196608
  float* f2   = ws + 196608;                          // 2*21*4096 = 172032
  float* otT  = ws + 196608 + 172032;                 // 196608
  float* lbuf = ws + 196608 + 172032 + 196608;        // 8192

  float* out0     = (float*)d_out;                    // 2*128*128*128
  float* corr_out = out0 + (size_t)NB * 128 * 128 * 128;  // 2*21*4096

  k_feat<<<dim3(HW / QT, 2), 256, 0, stream>>>(feat, w1, b1, w2, b2, out, f1T,
                                               f2, otT, lbuf, corr_out);
  k_stats<<<dim3(HW / PT, 4, 2), 256, 0, stream>>>(f1T, f2, lbuf);
  k_rows<<<dim3(4, 128, 2), 256, 0, stream>>>(f1T, f2, index, out0);
  k_corrout<<<dim3(8, HW / DPS, 2), 256, 0, stream>>>(f1T, f2, otT, lbuf,
                                                      corr_out);
  k_norm<<<dim3(128, 2), 1024, 0, stream>>>(out0);
}